// Round 1
// baseline (92.428 us; speedup 1.0000x reference)
//
#include <hip/hip_runtime.h>
#include <math.h>

// Problem constants (from reference: N=8192, M=100000, K=4096)
#define K_TOTAL 4096
#define N_RAYS  8192
#define S_CHUNKS 128
#define CHUNK (K_TOTAL / S_CHUNKS)     // 32 gaussians per K-chunk
#define R 4                            // rays per thread (register tile)
#define BLOCK 256
#define RAYS_PER_BLOCK (BLOCK * R)     // 1024
#define NGROUPS (N_RAYS / RAYS_PER_BLOCK)  // 8

// ---------------------------------------------------------------------------
// Kernel 1: transform table precompute (ONCE, to global — previously done
// redundantly per-block into LDS).
// Sigma = L L^T -> Sigma_inv = M^T M, M = L^-1 (forward substitution).
// Fold sqrt(0.5*log2e) into M (-> M'), b = -M'*mu, so the hot loop is
// y = M'*p + b, e = exp2(-||y||^2).
// Layout: 16 consecutive floats per k (64 B) so the main kernel's uniform
// reads merge into s_load_dwordx16.
// ---------------------------------------------------------------------------
__global__ __launch_bounds__(256) void table_kernel(
    const float* __restrict__ embeddings,
    const float* __restrict__ chol,
    const float* __restrict__ labels,
    const int*   __restrict__ idx,
    float*       __restrict__ tab)
{
    int k = blockIdx.x * 256 + threadIdx.x;
    if (k >= K_TOTAL) return;
    int i = idx[k];

    const float* Lp = chol + (size_t)i * 16;
    float l00 = Lp[0];
    float l10 = Lp[4],  l11 = Lp[5];
    float l20 = Lp[8],  l21 = Lp[9],  l22 = Lp[10];
    float l30 = Lp[12], l31 = Lp[13], l32 = Lp[14], l33 = Lp[15];

    float u0 = 1.0f / l00, u1 = 1.0f / l11, u2 = 1.0f / l22, u3 = 1.0f / l33;

    // M = L^-1 (lower triangular), forward substitution
    float m00 = u0;
    float m10 = -u1 * (l10 * m00);
    float m11 = u1;
    float m20 = -u2 * (l20 * m00 + l21 * m10);
    float m21 = -u2 * (l21 * m11);
    float m22 = u2;
    float m30 = -u3 * (l30 * m00 + l31 * m10 + l32 * m20);
    float m31 = -u3 * (l31 * m11 + l32 * m21);
    float m32 = -u3 * (l32 * m22);
    float m33 = u3;

    // scale by sqrt(0.5 * log2(e)) so exp(-0.5 q) == exp2(-||M' diff||^2)
    const float SC = 0.84932180381996511548f;
    m00 *= SC; m10 *= SC; m11 *= SC; m20 *= SC; m21 *= SC;
    m22 *= SC; m30 *= SC; m31 *= SC; m32 *= SC; m33 *= SC;

    float4 mu = *(const float4*)(embeddings + (size_t)i * 4);
    float b0 = -(m00 * mu.x);
    float b1 = -(m10 * mu.x + m11 * mu.y);
    float b2 = -(m20 * mu.x + m21 * mu.y + m22 * mu.z);
    float b3 = -(m30 * mu.x + m31 * mu.y + m32 * mu.z + m33 * mu.w);

    float lab = labels[i];

    float4* t = (float4*)(tab + (size_t)k * 16);
    t[0] = make_float4(m00, m10, m11, m20);
    t[1] = make_float4(m21, m22, m30, m31);
    t[2] = make_float4(m32, m33, b0, b1);
    t[3] = make_float4(b2, b3, lab, 0.0f);
}

// ---------------------------------------------------------------------------
// Kernel 2: main pair loop. Table reads are WAVE-UNIFORM (address depends
// only on the k loop counter + block index) through const __restrict__ ->
// compiler scalar-promotes them to s_load into SGPRs. No LDS, no
// __syncthreads, no per-lane VMEM in the hot loop: scalar-memory pipe feeds
// the tables while the VALU runs the 15-FMA + exp2 pair body.
// __launch_bounds__(256,4): 4 blocks/CU (16 waves/CU) co-resident.
// ---------------------------------------------------------------------------
__global__ __launch_bounds__(256, 4) void fused_main_kernel(
    const float* __restrict__ origins,
    const float* __restrict__ directions,
    const float* __restrict__ tab,
    float*       __restrict__ partial)
{
    int tid = threadIdx.x;
    int s   = blockIdx.y;

    int base = blockIdx.x * RAYS_PER_BLOCK + tid;   // ray of lane for r=0

    float p0[R], p1[R], p2[R], p3[R], acc[R];
    #pragma unroll
    for (int r = 0; r < R; ++r) {
        int n = base + r * BLOCK;
        float2 o = ((const float2*)origins)[n];
        float2 d = ((const float2*)directions)[n];
        p0[r] = o.x; p1[r] = o.y; p2[r] = d.x; p3[r] = d.y;
        acc[r] = 0.0f;
    }

    const float* __restrict__ tb = tab + (size_t)s * CHUNK * 16;

    #pragma unroll 2
    for (int k = 0; k < CHUNK; ++k) {
        const float* t = tb + k * 16;   // uniform address -> s_load_dwordx16
        float m00 = t[0],  m10 = t[1],  m11 = t[2],  m20 = t[3];
        float m21 = t[4],  m22 = t[5],  m30 = t[6],  m31 = t[7];
        float m32 = t[8],  m33 = t[9],  b0  = t[10], b1  = t[11];
        float b2  = t[12], b3  = t[13], lab = t[14];
        #pragma unroll
        for (int r = 0; r < R; ++r) {
            float y0 = fmaf(m00, p0[r], b0);
            float y1 = fmaf(m11, p1[r], fmaf(m10, p0[r], b1));
            float y2 = fmaf(m22, p2[r], fmaf(m21, p1[r], fmaf(m20, p0[r], b2)));
            float y3 = fmaf(m33, p3[r], fmaf(m32, p2[r], fmaf(m31, p1[r], fmaf(m30, p0[r], b3))));
            float sq = y0 * y0;
            sq = fmaf(y1, y1, sq);
            sq = fmaf(y2, y2, sq);
            sq = fmaf(y3, y3, sq);
            acc[r] = fmaf(lab, __builtin_amdgcn_exp2f(-sq), acc[r]);
        }
    }

    #pragma unroll
    for (int r = 0; r < R; ++r)
        partial[(size_t)s * N_RAYS + base + r * BLOCK] = acc[r];
}

// ---------------------------------------------------------------------------
// Kernel 3: reduce the S_CHUNKS partials per ray + sigmoid.
// Fully unrolled: 128 independent L2 loads in flight per thread (BW-bound,
// not latency-bound), pairwise tree sum. 128 blocks x 64 threads.
// sigmoid(x) = 1 / (1 + exp2(-x * log2e))
// ---------------------------------------------------------------------------
__global__ __launch_bounds__(64) void finish_kernel(
    const float* __restrict__ partial,
    float*       __restrict__ out)
{
    int n = blockIdx.x * 64 + threadIdx.x;
    float v[S_CHUNKS];
    #pragma unroll
    for (int s = 0; s < S_CHUNKS; ++s)
        v[s] = partial[(size_t)s * N_RAYS + n];
    // pairwise tree reduction (independent adds, log depth)
    #pragma unroll
    for (int w = S_CHUNKS / 2; w >= 1; w >>= 1)
        #pragma unroll
        for (int s = 0; s < w; ++s)
            v[s] += v[s + w];
    const float L2E = 1.44269504088896340736f;
    out[n] = 1.0f / (1.0f + __builtin_amdgcn_exp2f(-v[0] * L2E));
}

extern "C" void kernel_launch(void* const* d_in, const int* in_sizes, int n_in,
                              void* d_out, int out_size, void* d_ws, size_t ws_size,
                              hipStream_t stream) {
    const float* origins    = (const float*)d_in[0];
    const float* directions = (const float*)d_in[1];
    const float* embeddings = (const float*)d_in[2];
    const float* chol       = (const float*)d_in[3];
    const float* labels     = (const float*)d_in[4];
    const int*   idx        = (const int*)d_in[5];
    float* out = (float*)d_out;

    // workspace: [partials: 128*8192 float = 4 MB][table: 4096*16 float = 256 KB]
    float* partial = (float*)d_ws;
    float* tab     = (float*)((char*)d_ws + (size_t)S_CHUNKS * N_RAYS * sizeof(float));

    table_kernel<<<dim3(K_TOTAL / 256), dim3(256), 0, stream>>>(
        embeddings, chol, labels, idx, tab);

    fused_main_kernel<<<dim3(NGROUPS, S_CHUNKS), dim3(BLOCK), 0, stream>>>(
        origins, directions, tab, partial);

    finish_kernel<<<dim3(N_RAYS / 64), dim3(64), 0, stream>>>(partial, out);
}

// Round 3
// 85.313 us; speedup vs baseline: 1.0834x; 1.0834x over previous
//
#include <hip/hip_runtime.h>
#include <math.h>

// Problem constants (from reference: N=8192, M=100000, K=4096)
#define K_TOTAL 4096
#define N_RAYS  8192
#define S_CHUNKS 128
#define CHUNK (K_TOTAL / S_CHUNKS)     // 32 gaussians per K-chunk
#define R 4                            // rays per thread (2 packed pairs)
#define BLOCK 256
#define RAYS_PER_BLOCK (BLOCK * R)     // 1024
#define NGROUPS (N_RAYS / RAYS_PER_BLOCK)  // 8

// ---------------------------------------------------------------------------
// CDNA4 packed dual-f32 ops (VOP3P). hipcc never auto-packs f32.
// op_sel[i]   : which half of src i feeds the LOW  result (0=lo, 1=hi)
// op_sel_hi[i]: which half of src i feeds the HIGH result (0=lo, 1=hi)
// Elementwise default = op_sel:[0,0,0] op_sel_hi:[1,1,1].
// Broadcast-lo of src i: both bits 0. Broadcast-hi of src i: both bits 1.
// Per-lane IEEE fma -> bit-identical to the scalar fmaf version.
// Naming: pk_fma_<A><C> where A=sel for src0 (coef), C=sel for src2 (b/acc),
//         L=bcast lo, H=bcast hi, E=elementwise. src1 (ray pair) always E.
// ---------------------------------------------------------------------------
#define PK_FMA(NAME, MODS)                                                \
__device__ inline float2 NAME(float2 a, float2 b, float2 c) {             \
    float2 d;                                                             \
    asm("v_pk_fma_f32 %0, %1, %2, %3 " MODS                               \
        : "=v"(d) : "v"(a), "v"(b), "v"(c));                              \
    return d;                                                             \
}
PK_FMA(pk_fma_LL, "op_sel:[0,0,0] op_sel_hi:[0,1,0]")
PK_FMA(pk_fma_HH, "op_sel:[1,0,1] op_sel_hi:[1,1,1]")
PK_FMA(pk_fma_LE, "op_sel:[0,0,0] op_sel_hi:[0,1,1]")
PK_FMA(pk_fma_HE, "op_sel:[1,0,0] op_sel_hi:[1,1,1]")
PK_FMA(pk_fma_HL, "op_sel:[1,0,0] op_sel_hi:[1,1,0]")
PK_FMA(pk_fma_LH, "op_sel:[0,0,1] op_sel_hi:[0,1,1]")
PK_FMA(pk_fma_EE, "")

__device__ inline float2 pk_mul(float2 a, float2 b) {
    float2 d;
    asm("v_pk_mul_f32 %0, %1, %2" : "=v"(d) : "v"(a), "v"(b));
    return d;
}

// ---------------------------------------------------------------------------
// Main kernel (round-0 proven structure + packed hot loop).
// Phase 0: threads 0..31 build the transform table: M' = SC * L^-1 (forward
//   substitution), b = -M'*mu, stored COMPACT as 8 float2 pairs per k:
//   q0=(m00,m10) q1=(m11,m20) q2=(m21,m22) q3=(m30,m31)
//   q4=(m32,m33) q5=(b0,b1)  q6=(b2,b3)  q7=(lab,0)
// Hot loop: y = M'p + b for 2 rays per packed op via op_sel broadcasts;
//   e = exp2(-||y||^2) (exp(-0.5 q) with SC folded into M').
// LDS reads wave-uniform -> broadcast, conflict-free; 8x ds_read_b64 per k
// (same LDS-pipe cost as round-0's 4x b128), VALU halved vs scalar.
// ---------------------------------------------------------------------------
__global__ __launch_bounds__(256, 4) void fused_main_kernel(
    const float* __restrict__ origins,
    const float* __restrict__ directions,
    const float* __restrict__ embeddings,
    const float* __restrict__ chol,
    const float* __restrict__ labels,
    const int*   __restrict__ idx,
    float*       __restrict__ partial)
{
    __shared__ float2 stab[CHUNK * 8];   // 2 KB

    int tid = threadIdx.x;
    int s   = blockIdx.y;

    if (tid < CHUNK) {
        int k = s * CHUNK + tid;
        int i = idx[k];

        const float* Lp = chol + (size_t)i * 16;
        float l00 = Lp[0];
        float l10 = Lp[4],  l11 = Lp[5];
        float l20 = Lp[8],  l21 = Lp[9],  l22 = Lp[10];
        float l30 = Lp[12], l31 = Lp[13], l32 = Lp[14], l33 = Lp[15];

        float u0 = 1.0f / l00, u1 = 1.0f / l11, u2 = 1.0f / l22, u3 = 1.0f / l33;

        // M = L^-1 (lower triangular), forward substitution
        float m00 = u0;
        float m10 = -u1 * (l10 * m00);
        float m11 = u1;
        float m20 = -u2 * (l20 * m00 + l21 * m10);
        float m21 = -u2 * (l21 * m11);
        float m22 = u2;
        float m30 = -u3 * (l30 * m00 + l31 * m10 + l32 * m20);
        float m31 = -u3 * (l31 * m11 + l32 * m21);
        float m32 = -u3 * (l32 * m22);
        float m33 = u3;

        // scale by sqrt(0.5 * log2(e)) so exp(-0.5 q) == exp2(-||M' diff||^2)
        const float SC = 0.84932180381996511548f;
        m00 *= SC; m10 *= SC; m11 *= SC; m20 *= SC; m21 *= SC;
        m22 *= SC; m30 *= SC; m31 *= SC; m32 *= SC; m33 *= SC;

        float4 mu = *(const float4*)(embeddings + (size_t)i * 4);
        float b0 = -(m00 * mu.x);
        float b1 = -(m10 * mu.x + m11 * mu.y);
        float b2 = -(m20 * mu.x + m21 * mu.y + m22 * mu.z);
        float b3 = -(m30 * mu.x + m31 * mu.y + m32 * mu.z + m33 * mu.w);

        float lab = labels[i];

        stab[tid*8 + 0] = make_float2(m00, m10);
        stab[tid*8 + 1] = make_float2(m11, m20);
        stab[tid*8 + 2] = make_float2(m21, m22);
        stab[tid*8 + 3] = make_float2(m30, m31);
        stab[tid*8 + 4] = make_float2(m32, m33);
        stab[tid*8 + 5] = make_float2(b0,  b1);
        stab[tid*8 + 6] = make_float2(b2,  b3);
        stab[tid*8 + 7] = make_float2(lab, 0.0f);
    }

    int base = blockIdx.x * RAYS_PER_BLOCK + tid;   // ray of lane for r=0

    // Pair p covers rays (base + 2p*BLOCK, base + (2p+1)*BLOCK) in (lo, hi)
    float2 P0[2], P1[2], P2[2], P3[2];
    float acc[R];
    #pragma unroll
    for (int p = 0; p < 2; ++p) {
        int n0 = base + (2*p)     * BLOCK;
        int n1 = base + (2*p + 1) * BLOCK;
        float2 o0 = ((const float2*)origins)[n0];
        float2 d0 = ((const float2*)directions)[n0];
        float2 o1 = ((const float2*)origins)[n1];
        float2 d1 = ((const float2*)directions)[n1];
        P0[p] = make_float2(o0.x, o1.x);
        P1[p] = make_float2(o0.y, o1.y);
        P2[p] = make_float2(d0.x, d1.x);
        P3[p] = make_float2(d0.y, d1.y);
        acc[2*p] = 0.0f; acc[2*p+1] = 0.0f;
    }

    __syncthreads();

    #pragma unroll 4
    for (int k = 0; k < CHUNK; ++k) {
        float2 q0 = stab[k*8 + 0];   // (m00, m10)
        float2 q1 = stab[k*8 + 1];   // (m11, m20)
        float2 q2 = stab[k*8 + 2];   // (m21, m22)
        float2 q3 = stab[k*8 + 3];   // (m30, m31)
        float2 q4 = stab[k*8 + 4];   // (m32, m33)
        float2 q5 = stab[k*8 + 5];   // (b0,  b1)
        float2 q6 = stab[k*8 + 6];   // (b2,  b3)
        float2 q7 = stab[k*8 + 7];   // (lab, 0)
        float  lab = q7.x;
        #pragma unroll
        for (int p = 0; p < 2; ++p) {
            float2 y0 = pk_fma_LL(q0, P0[p], q5);                 // m00*p0 + b0
            float2 y1 = pk_fma_HH(q0, P0[p], q5);                 // m10*p0 + b1
            y1 = pk_fma_LE(q1, P1[p], y1);                        // + m11*p1
            float2 y2 = pk_fma_HL(q1, P0[p], q6);                 // m20*p0 + b2
            y2 = pk_fma_LE(q2, P1[p], y2);                        // + m21*p1
            y2 = pk_fma_HE(q2, P2[p], y2);                        // + m22*p2
            float2 y3 = pk_fma_LH(q3, P0[p], q6);                 // m30*p0 + b3
            y3 = pk_fma_HE(q3, P1[p], y3);                        // + m31*p1
            y3 = pk_fma_LE(q4, P2[p], y3);                        // + m32*p2
            y3 = pk_fma_HE(q4, P3[p], y3);                        // + m33*p3
            float2 sq = pk_mul(y0, y0);
            sq = pk_fma_EE(y1, y1, sq);
            sq = pk_fma_EE(y2, y2, sq);
            sq = pk_fma_EE(y3, y3, sq);
            acc[2*p]     = fmaf(lab, __builtin_amdgcn_exp2f(-sq.x), acc[2*p]);
            acc[2*p + 1] = fmaf(lab, __builtin_amdgcn_exp2f(-sq.y), acc[2*p + 1]);
        }
    }

    #pragma unroll
    for (int r = 0; r < R; ++r)
        partial[(size_t)s * N_RAYS + base + r * BLOCK] = acc[r];
}

// ---------------------------------------------------------------------------
// Finish: reduce the S_CHUNKS partials per ray + sigmoid.
// Fully unrolled: 128 independent L2 loads in flight per thread (BW-bound,
// not latency-bound), pairwise tree sum. 128 blocks x 64 threads.
// sigmoid(x) = 1 / (1 + exp2(-x * log2e))
// ---------------------------------------------------------------------------
__global__ __launch_bounds__(64) void finish_kernel(
    const float* __restrict__ partial,
    float*       __restrict__ out)
{
    int n = blockIdx.x * 64 + threadIdx.x;
    float v[S_CHUNKS];
    #pragma unroll
    for (int s = 0; s < S_CHUNKS; ++s)
        v[s] = partial[(size_t)s * N_RAYS + n];
    // pairwise tree reduction (independent adds, log depth)
    #pragma unroll
    for (int w = S_CHUNKS / 2; w >= 1; w >>= 1)
        #pragma unroll
        for (int s = 0; s < w; ++s)
            v[s] += v[s + w];
    const float L2E = 1.44269504088896340736f;
    out[n] = 1.0f / (1.0f + __builtin_amdgcn_exp2f(-v[0] * L2E));
}

extern "C" void kernel_launch(void* const* d_in, const int* in_sizes, int n_in,
                              void* d_out, int out_size, void* d_ws, size_t ws_size,
                              hipStream_t stream) {
    const float* origins    = (const float*)d_in[0];
    const float* directions = (const float*)d_in[1];
    const float* embeddings = (const float*)d_in[2];
    const float* chol       = (const float*)d_in[3];
    const float* labels     = (const float*)d_in[4];
    const int*   idx        = (const int*)d_in[5];
    float* out = (float*)d_out;

    // workspace: [partials: 128*8192 float = 4 MB]
    float* partial = (float*)d_ws;

    fused_main_kernel<<<dim3(NGROUPS, S_CHUNKS), dim3(BLOCK), 0, stream>>>(
        origins, directions, embeddings, chol, labels, idx, partial);

    finish_kernel<<<dim3(N_RAYS / 64), dim3(64), 0, stream>>>(partial, out);
}